// Round 20
// baseline (99.176 us; speedup 1.0000x reference)
//
#include <hip/hip_runtime.h>
#include <hip/hip_bf16.h>

#define NB 2
#define NN 2048
#define NC 1024
#define NH 16
#define ND 64
#define LOG2E 1.4426950408889634f
#define NSPLIT 2

typedef __attribute__((ext_vector_type(4))) float f32x4;
typedef __attribute__((ext_vector_type(16))) float f32x16;
typedef __attribute__((ext_vector_type(8))) short bf16x8;
typedef __attribute__((ext_vector_type(4))) unsigned short us4;
typedef __attribute__((ext_vector_type(8))) unsigned short us8;
typedef __attribute__((ext_vector_type(4))) unsigned int u32x4;

#define MFMA32 __builtin_amdgcn_mfma_f32_32x32x16_bf16
#define MFMA16 __builtin_amdgcn_mfma_f32_16x16x32_bf16

// 2^x: compiler-visible intrinsic preferred (R13 lesson)
#if __has_builtin(__builtin_amdgcn_exp2f)
#define EX2(x) __builtin_amdgcn_exp2f(x)
#else
__device__ __forceinline__ float ex2_asm(float x) {
    float r;
    asm volatile("v_exp_f32 %0, %1\n\ts_nop 1" : "=v"(r) : "v"(x));
    return r;
}
#define EX2(x) ex2_asm(x)
#endif

// async global -> LDS, 16B per lane; lds base must be wave-uniform
__device__ __forceinline__ void load_lds16(const unsigned short* g, unsigned short* l) {
    __builtin_amdgcn_global_load_lds(
        (const __attribute__((address_space(1))) unsigned int*)g,
        (__attribute__((address_space(3))) unsigned int*)l, 16, 0, 0);
}

__device__ __forceinline__ unsigned short f2bf(float f) {  // integer RNE
    unsigned int u = __builtin_bit_cast(unsigned int, f);
    u = (u + 0x7FFFu + ((u >> 16) & 1u)) >> 16;
    return (unsigned short)u;
}
__device__ __forceinline__ float bf2f(unsigned short h) {
    return __builtin_bit_cast(float, (unsigned int)h << 16);
}
__device__ __forceinline__ unsigned short f2bf_hw(float f) {
    __hip_bfloat16 b = __float2bfloat16(f);
    unsigned short u;
    __builtin_memcpy(&u, &b, 2);
    return u;
}
// pack two f32 -> dword of 2 bf16, single HW instruction (VOP3 VALU)
__device__ __forceinline__ unsigned int pk2(float lo, float hi) {
    unsigned int r;
    asm("v_cvt_pk_bf16_f32 %0, %1, %2" : "=v"(r) : "v"(lo), "v"(hi));
    return r;
}

// ---------- K and V -> fragment-major bf16 (fused prep) ----------
__global__ __launch_bounds__(256) void kvf_kernel(const float* __restrict__ k,
                                                  const float* __restrict__ v,
                                                  unsigned short* __restrict__ kf,
                                                  unsigned short* __restrict__ vf) {
    __shared__ float T[32][68];
    const int bh = blockIdx.y, c = blockIdx.x, t = threadIdx.x;
    {
        const int row = t >> 3;
        const int g = t & 7;
        const float* src = k + ((size_t)bh * NN + c * 32 + row) * ND + g * 8;
        f32x4 x0 = *reinterpret_cast<const f32x4*>(src);
        f32x4 x1 = *reinterpret_cast<const f32x4*>(src + 4);
        us8 h;
        #pragma unroll
        for (int j = 0; j < 4; ++j) {
            h[j] = f2bf(x0[j]);
            h[4 + j] = f2bf(x1[j]);
        }
        const size_t fo = ((size_t)bh * 64 + c) * 2048 + g * 256 + row * 8;
        *reinterpret_cast<us8*>(kf + fo) = h;
    }
    {
        const int row = t >> 3, d0 = (t & 7) * 8;
        const float* src = v + ((size_t)bh * NN + c * 32 + row) * ND + d0;
        f32x4 a = *reinterpret_cast<const f32x4*>(src);
        f32x4 b2 = *reinterpret_cast<const f32x4*>(src + 4);
        *reinterpret_cast<f32x4*>(&T[row][d0]) = a;
        *reinterpret_cast<f32x4*>(&T[row][d0 + 4]) = b2;
    }
    __syncthreads();
    {
        const int g2 = t >> 6, hi = (t >> 5) & 1, l31 = t & 31;
        const int ks2 = g2 & 1, dt = g2 >> 1;
        us8 r;
        #pragma unroll
        for (int j = 0; j < 8; ++j) r[j] = f2bf(T[ks2 * 16 + hi * 8 + j][dt * 32 + l31]);
        const size_t fo = ((size_t)bh * 64 + c) * 2048 + (g2 * 2 + hi) * 256 + l31 * 8;
        *reinterpret_cast<us8*>(vf + fo) = r;
    }
}

// ---------- W -> fragment-major bf16 ----------
__global__ __launch_bounds__(256) void wf_kernel(const float* __restrict__ w,
                                                 unsigned short* __restrict__ wf) {
    const int tid = blockIdx.x * 256 + threadIdx.x;  // 512 blocks
    const int ot = tid >> 11;
    const int s = tid & 2047;
    const int cc = s >> 6;
    const int lane = s & 63;
    const int l15 = lane & 15, lhi = lane >> 4;
    const float* src = w + (size_t)(ot * 16 + l15) * NC + cc * 32 + lhi * 8;
    f32x4 x0 = *reinterpret_cast<const f32x4*>(src);
    f32x4 x1 = *reinterpret_cast<const f32x4*>(src + 4);
    us8 r;
    #pragma unroll
    for (int j = 0; j < 4; ++j) {
        r[j] = f2bf(x0[j]);
        r[4 + j] = f2bf(x1[j]);
    }
    *reinterpret_cast<us8*>(wf + (size_t)tid * 8) = r;
}

// stage chunk CI into buffer BUF
#define STAGE(CI, BUF)                                                   \
    {                                                                    \
        load_lds16(KpT + (size_t)(CI) * 2048, &sK[BUF][wave * 512]);     \
        load_lds16(VpT + (size_t)(CI) * 2048, &sV[BUF][wave * 512]);     \
    }

// one pipelined iteration (R18 schedule) + T5 setprio around MFMA clusters
#define ATTN_ITER(CI, CUR, NXT2)                                                       \
    {                                                                                  \
        if ((CI) < 30) STAGE((CI) + 2, NXT2);                                          \
        const unsigned short* Kb = &sK[CUR][fo];                                       \
        const unsigned short* Vb = &sV[CUR][fo];                                       \
        f32x16 sa;                                                                     \
        _Pragma("unroll")                                                              \
        for (int r = 0; r < 16; ++r) sa[r] = 0.f;                                      \
        __builtin_amdgcn_s_setprio(1);                                                 \
        _Pragma("unroll")                                                              \
        for (int ks = 0; ks < 4; ++ks) {                                               \
            bf16x8 kk = *reinterpret_cast<const bf16x8*>(Kb + ks * 512);               \
            sa = MFMA32(kk, qh[ks], sa, 0, 0, 0);                                      \
        }                                                                              \
        __builtin_amdgcn_s_setprio(0);                                                 \
        _Pragma("unroll")                                                              \
        for (int r = 0; r < 16; r += 4) {                                              \
            float e0 = EX2(sa[r]);                                                     \
            float e1 = EX2(sa[r + 1]);                                                 \
            float e2 = EX2(sa[r + 2]);                                                 \
            float e3 = EX2(sa[r + 3]);                                                 \
            sa[r] = e0; sa[r + 1] = e1; sa[r + 2] = e2; sa[r + 3] = e3;                \
            rs0 += e0; rs1 += e1; rs2 += e2; rs3 += e3;                                \
        }                                                                              \
        _Pragma("unroll")                                                              \
        for (int ks2 = 0; ks2 < 2; ++ks2) {                                            \
            unsigned int sA = pk2(sa[8 * ks2 + 0], sa[8 * ks2 + 1]);                   \
            unsigned int sB = pk2(sa[8 * ks2 + 2], sa[8 * ks2 + 3]);                   \
            unsigned int sC = pk2(sa[8 * ks2 + 4], sa[8 * ks2 + 5]);                   \
            unsigned int sD = pk2(sa[8 * ks2 + 6], sa[8 * ks2 + 7]);                   \
            unsigned int snd0 = hi ? sA : sC;                                          \
            unsigned int snd1 = hi ? sB : sD;                                          \
            unsigned int rcv0 = __shfl_xor(snd0, 32);                                  \
            unsigned int rcv1 = __shfl_xor(snd1, 32);                                  \
            u32x4 uf;                                                                  \
            uf[0] = hi ? rcv0 : sA;                                                    \
            uf[1] = hi ? rcv1 : sB;                                                    \
            uf[2] = hi ? sC : rcv0;                                                    \
            uf[3] = hi ? sD : rcv1;                                                    \
            bf16x8 pfrag = __builtin_bit_cast(bf16x8, uf);                             \
            bf16x8 v0 = *reinterpret_cast<const bf16x8*>(Vb + (0 * 2 + ks2) * 512);    \
            bf16x8 v1 = *reinterpret_cast<const bf16x8*>(Vb + (1 * 2 + ks2) * 512);    \
            __builtin_amdgcn_s_setprio(1);                                             \
            acc0 = MFMA32(v0, pfrag, acc0, 0, 0, 0);                                   \
            acc1 = MFMA32(v1, pfrag, acc1, 0, 0, 0);                                   \
            __builtin_amdgcn_s_setprio(0);                                             \
        }                                                                              \
        if ((CI) < 31) {                                                               \
            if ((CI) == 30) asm volatile("s_waitcnt vmcnt(0)" ::: "memory");           \
            else            asm volatile("s_waitcnt vmcnt(2)" ::: "memory");           \
            __builtin_amdgcn_s_barrier();                                              \
        }                                                                              \
    }

// ---------- fused flash attention: counted-vmcnt 3-buffer LDS pipeline + setprio ----------
// grid: 1024 = 32 bh x 16 q-tiles x 2 kv-splits; block 256 (4 waves x 32 q-rows)
__global__ __launch_bounds__(256, 2) void attn_kernel(const float* __restrict__ q,
                                                      const unsigned short* __restrict__ kf,
                                                      const unsigned short* __restrict__ vf,
                                                      unsigned short* __restrict__ po,
                                                      float* __restrict__ pl) {
    __shared__ __align__(16) unsigned short sK[3][2048];
    __shared__ __align__(16) unsigned short sV[3][2048];
    const size_t X_ELEMS = (size_t)NB * NN * NC;
    const size_t ML_ELEMS = (size_t)NB * NN * NH;
    const int bid = blockIdx.x;
    const int swz = (bid & 7) * 128 + (bid >> 3);
    const int bh = swz >> 5;
    const int qt = (swz & 31) >> 1;
    const int split = swz & 1;
    const int b = bh >> 4, h = bh & 15;
    const int t = threadIdx.x;
    const int wave = t >> 6, lane = t & 63;
    const int l31 = lane & 31, hi = lane >> 5;
    const int qrow = qt * 128 + wave * 32 + l31;

    // ---- Q row (x log2e) -> bf16 B-fragments ----
    bf16x8 qh[4];
    {
        const float* qp = q + ((size_t)(b * NN + qrow)) * NC + h * ND;
        #pragma unroll
        for (int ks = 0; ks < 4; ++ks) {
            int d = ks * 16 + hi * 8;
            f32x4 x0 = *reinterpret_cast<const f32x4*>(qp + d);
            f32x4 x1 = *reinterpret_cast<const f32x4*>(qp + d + 4);
            bf16x8 ah;
            #pragma unroll
            for (int j = 0; j < 4; ++j) {
                ah[j] = (short)f2bf_hw(x0[j] * LOG2E);
                ah[4 + j] = (short)f2bf_hw(x1[j] * LOG2E);
            }
            qh[ks] = ah;
        }
    }

    f32x16 acc0, acc1;
    #pragma unroll
    for (int r = 0; r < 16; ++r) { acc0[r] = 0.f; acc1[r] = 0.f; }
    float rs0 = 0.f, rs1 = 0.f, rs2 = 0.f, rs3 = 0.f;

    const unsigned short* KpT = kf + (size_t)(bh * 64 + split * 32) * 2048 + (size_t)t * 8;
    const unsigned short* VpT = vf + (size_t)(bh * 64 + split * 32) * 2048 + (size_t)t * 8;
    const int fo = hi * 256 + l31 * 8;

    // prologue: stage chunks 0,1; wait only for chunk 0
    STAGE(0, 0)
    STAGE(1, 1)
    asm volatile("s_waitcnt vmcnt(2)" ::: "memory");
    __builtin_amdgcn_s_barrier();

    for (int base = 0; base < 30; base += 3) {
        ATTN_ITER(base, 0, 2)
        ATTN_ITER(base + 1, 1, 0)
        ATTN_ITER(base + 2, 2, 1)
    }
    ATTN_ITER(30, 0, 2)
    ATTN_ITER(31, 1, 0)

    // ---- epilogue: split-local sum, normalize, redistribute, fragment-major store ----
    float rs = (rs0 + rs1) + (rs2 + rs3);
    rs += __shfl_xor(rs, 32);
    const float inv = 1.0f / rs;

    unsigned short* pob = po + (size_t)split * X_ELEMS;
    float* plb = pl + (size_t)split * ML_ELEMS;
    const int el15 = l31 & 15;
    const int nt = b * 128 + qt * 8 + wave * 2 + (l31 >> 4);
    #pragma unroll
    for (int dt = 0; dt < 2; ++dt) {
        const f32x16 a = (dt == 0) ? acc0 : acc1;
        unsigned int P0 = pk2(a[0] * inv, a[1] * inv);
        unsigned int P1 = pk2(a[2] * inv, a[3] * inv);
        unsigned int P2 = pk2(a[4] * inv, a[5] * inv);
        unsigned int P3 = pk2(a[6] * inv, a[7] * inv);
        unsigned int P4 = pk2(a[8] * inv, a[9] * inv);
        unsigned int P5 = pk2(a[10] * inv, a[11] * inv);
        unsigned int P6 = pk2(a[12] * inv, a[13] * inv);
        unsigned int P7 = pk2(a[14] * inv, a[15] * inv);
        unsigned int r0 = __shfl_xor(hi ? P0 : P4, 32);
        unsigned int r1 = __shfl_xor(hi ? P1 : P5, 32);
        unsigned int r2 = __shfl_xor(hi ? P2 : P6, 32);
        unsigned int r3 = __shfl_xor(hi ? P3 : P7, 32);
        u32x4 c0, c1;
        c0[0] = hi ? r0 : P0;
        c0[1] = hi ? r1 : P1;
        c0[2] = hi ? P4 : r0;
        c0[3] = hi ? P5 : r1;
        c1[0] = hi ? r2 : P2;
        c1[1] = hi ? r3 : P3;
        c1[2] = hi ? P6 : r2;
        c1[3] = hi ? P7 : r3;
        unsigned short* base_ = pob + (size_t)(nt * 32 + h * 2 + dt) * 512;
        *reinterpret_cast<u32x4*>(base_ + (hi * 32 + el15) * 8) = c0;
        *reinterpret_cast<u32x4*>(base_ + (hi * 32 + 16 + el15) * 8) = c1;
    }
    if (hi == 0) {
        plb[(size_t)(b * NN + qrow) * NH + h] = rs;
    }
}

// ---------- combine: blend KV-split partials once, fragment-major in/out ----------
__global__ __launch_bounds__(256) void combine_kernel(const unsigned short* __restrict__ po,
                                                      const float* __restrict__ pl,
                                                      unsigned short* __restrict__ xf) {
    const size_t X_ELEMS = (size_t)NB * NN * NC;
    const size_t ML_ELEMS = (size_t)NB * NN * NH;
    const int tid = blockIdx.x * 256 + threadIdx.x;  // 1024 blocks
    const int nt = tid >> 10;
    const int v = tid & 1023;
    const int h = v >> 6;
    const int lane = v & 63;
    const int row = nt * 16 + (lane & 15);
    float w[NSPLIT];
    {
        float lsum = 0.f;
        #pragma unroll
        for (int i = 0; i < NSPLIT; ++i) {
            w[i] = pl[(size_t)i * ML_ELEMS + (size_t)row * NH + h];
            lsum += w[i];
        }
        float inv = 1.0f / lsum;
        #pragma unroll
        for (int i = 0; i < NSPLIT; ++i) w[i] *= inv;
    }
    const size_t s0 = (size_t)(nt * 32 + h * 2) * 512 + lane * 8;
    const size_t s1 = s0 + 512;
    float f0[8], f1[8];
    #pragma unroll
    for (int j = 0; j < 8; ++j) { f0[j] = 0.f; f1[j] = 0.f; }
    #pragma unroll
    for (int i = 0; i < NSPLIT; ++i) {
        us8 e0 = *reinterpret_cast<const us8*>(po + (size_t)i * X_ELEMS + s0);
        us8 e1 = *reinterpret_cast<const us8*>(po + (size_t)i * X_ELEMS + s1);
        #pragma unroll
        for (int j = 0; j < 8; ++j) {
            f0[j] += w[i] * bf2f(e0[j]);
            f1[j] += w[i] * bf2f(e1[j]);
        }
    }
    us8 o0_, o1_;
    #pragma unroll
    for (int j = 0; j < 8; ++j) {
        o0_[j] = f2bf_hw(f0[j]);
        o1_[j] = f2bf_hw(f1[j]);
    }
    *reinterpret_cast<us8*>(xf + s0) = o0_;
    *reinterpret_cast<us8*>(xf + s1) = o1_;
}

// ---------- projection GEMM: fragment-major, 1 n-tile/wave, 1024 blocks for TLP ----------
// grid 1024 = 64 n-tiles(64 rows) x 16 o-tiles(64); block 256 (4 waves)
__global__ __launch_bounds__(256, 2) void proj_kernel(const unsigned short* __restrict__ xf,
                                                      const unsigned short* __restrict__ wf,
                                                      const float* __restrict__ bias,
                                                      float* __restrict__ out) {
    const int bid = blockIdx.x;
    const int swz = (bid & 7) * 128 + (bid >> 3);
    const int bx = swz >> 4;    // 0..63 n-super-tile (64 rows)
    const int by = swz & 15;    // o-tile
    const int wave = threadIdx.x >> 6, lane = threadIdx.x & 63;
    const int l15 = lane & 15, lhi = lane >> 4;
    const int nt0 = bx * 4 + wave;  // one 16-row fragment tile per wave
    const int ot0 = by * 4;

    const unsigned short* xA = xf + (size_t)nt0 * 32 * 512 + lane * 8;
    const unsigned short* wB = wf + (size_t)ot0 * 32 * 512 + lane * 8;

    f32x4 acc[4];
    #pragma unroll
    for (int c = 0; c < 4; ++c) acc[c] = (f32x4){0.f, 0.f, 0.f, 0.f};

    bf16x8 a0 = *reinterpret_cast<const bf16x8*>(xA);
    bf16x8 bfr[4];
    #pragma unroll
    for (int cb = 0; cb < 4; ++cb)
        bfr[cb] = *reinterpret_cast<const bf16x8*>(wB + (size_t)cb * 32 * 512);

    for (int cc = 0; cc < 32; ++cc) {
        const int ccn = (cc < 31) ? cc + 1 : 31;
        bf16x8 a0n = *reinterpret_cast<const bf16x8*>(xA + (size_t)ccn * 512);
        bf16x8 bn[4];
        #pragma unroll
        for (int cb = 0; cb < 4; ++cb)
            bn[cb] = *reinterpret_cast<const bf16x8*>(wB + (size_t)(cb * 32 + ccn) * 512);
        #pragma unroll
        for (int cb = 0; cb < 4; ++cb)
            acc[cb] = MFMA16(a0, bfr[cb], acc[cb], 0, 0, 0);
        a0 = a0n;
        #pragma unroll
        for (int cb = 0; cb < 4; ++cb) bfr[cb] = bn[cb];
    }
    #pragma unroll
    for (int cb = 0; cb < 4; ++cb)
        #pragma unroll
        for (int v = 0; v < 4; ++v) {
            int n = nt0 * 16 + lhi * 4 + v;
            int o = by * 64 + cb * 16 + l15;
            out[(size_t)n * NC + o] = acc[cb][v] + bias[o];
        }
}

extern "C" void kernel_launch(void* const* d_in, const int* in_sizes, int n_in,
                              void* d_out, int out_size, void* d_ws, size_t ws_size,
                              hipStream_t stream) {
    const float* q    = (const float*)d_in[0];
    const float* k    = (const float*)d_in[1];
    const float* v    = (const float*)d_in[2];
    const float* w    = (const float*)d_in[3];
    const float* bias = (const float*)d_in[4];
    float* out = (float*)d_out;

    const size_t KV_ELEMS = (size_t)NB * NH * NN * ND;  // 4,194,304
    const size_t X_ELEMS  = (size_t)NB * NN * NC;       // 4,194,304
    const size_t W_ELEMS  = (size_t)NC * NC;            // 1,048,576
    const size_t ML_ELEMS = (size_t)NB * NN * NH;       // 65,536

    unsigned short* kfb = (unsigned short*)d_ws;
    unsigned short* vfb = kfb + KV_ELEMS;
    unsigned short* wfb = vfb + KV_ELEMS;
    unsigned short* pob = wfb + W_ELEMS;                 // 2 splits
    unsigned short* xfb = pob + (size_t)NSPLIT * X_ELEMS;
    float* plb = (float*)(xfb + X_ELEMS);                // 2 splits

    dim3 fg(NN / 32, NB * NH);
    kvf_kernel<<<fg, 256, 0, stream>>>(k, v, kfb, vfb);
    wf_kernel<<<512, 256, 0, stream>>>(w, wfb);

    attn_kernel<<<1024, 256, 0, stream>>>(q, kfb, vfb, pob, plb);
    combine_kernel<<<1024, 256, 0, stream>>>(pob, plb, xfb);

    proj_kernel<<<1024, 256, 0, stream>>>(xfb, wfb, bias, out);
}

// Round 21
// 90.502 us; speedup vs baseline: 1.0958x; 1.0958x over previous
//
#include <hip/hip_runtime.h>
#include <hip/hip_bf16.h>

#define NB 2
#define NN 2048
#define NC 1024
#define NH 16
#define ND 64
#define LOG2E 1.4426950408889634f
#define NSPLIT 2

typedef __attribute__((ext_vector_type(4))) float f32x4;
typedef __attribute__((ext_vector_type(16))) float f32x16;
typedef __attribute__((ext_vector_type(8))) short bf16x8;
typedef __attribute__((ext_vector_type(4))) unsigned short us4;
typedef __attribute__((ext_vector_type(8))) unsigned short us8;
typedef __attribute__((ext_vector_type(4))) unsigned int u32x4;

#define MFMA32 __builtin_amdgcn_mfma_f32_32x32x16_bf16
#define MFMA16 __builtin_amdgcn_mfma_f32_16x16x32_bf16

// 2^x: compiler-visible intrinsic preferred (R13 lesson)
#if __has_builtin(__builtin_amdgcn_exp2f)
#define EX2(x) __builtin_amdgcn_exp2f(x)
#else
__device__ __forceinline__ float ex2_asm(float x) {
    float r;
    asm volatile("v_exp_f32 %0, %1\n\ts_nop 1" : "=v"(r) : "v"(x));
    return r;
}
#define EX2(x) ex2_asm(x)
#endif

// async global -> LDS, 16B per lane; lds base must be wave-uniform
__device__ __forceinline__ void load_lds16(const unsigned short* g, unsigned short* l) {
    __builtin_amdgcn_global_load_lds(
        (const __attribute__((address_space(1))) unsigned int*)g,
        (__attribute__((address_space(3))) unsigned int*)l, 16, 0, 0);
}

__device__ __forceinline__ unsigned short f2bf(float f) {  // integer RNE
    unsigned int u = __builtin_bit_cast(unsigned int, f);
    u = (u + 0x7FFFu + ((u >> 16) & 1u)) >> 16;
    return (unsigned short)u;
}
__device__ __forceinline__ float bf2f(unsigned short h) {
    return __builtin_bit_cast(float, (unsigned int)h << 16);
}
__device__ __forceinline__ unsigned short f2bf_hw(float f) {
    __hip_bfloat16 b = __float2bfloat16(f);
    unsigned short u;
    __builtin_memcpy(&u, &b, 2);
    return u;
}
// pack two f32 -> dword of 2 bf16, single HW instruction (VOP3 VALU)
__device__ __forceinline__ unsigned int pk2(float lo, float hi) {
    unsigned int r;
    asm("v_cvt_pk_bf16_f32 %0, %1, %2" : "=v"(r) : "v"(lo), "v"(hi));
    return r;
}

// ---------- K and V -> fragment-major bf16 (fused prep) ----------
__global__ __launch_bounds__(256) void kvf_kernel(const float* __restrict__ k,
                                                  const float* __restrict__ v,
                                                  unsigned short* __restrict__ kf,
                                                  unsigned short* __restrict__ vf) {
    __shared__ float T[32][68];
    const int bh = blockIdx.y, c = blockIdx.x, t = threadIdx.x;
    {
        const int row = t >> 3;
        const int g = t & 7;
        const float* src = k + ((size_t)bh * NN + c * 32 + row) * ND + g * 8;
        f32x4 x0 = *reinterpret_cast<const f32x4*>(src);
        f32x4 x1 = *reinterpret_cast<const f32x4*>(src + 4);
        us8 h;
        #pragma unroll
        for (int j = 0; j < 4; ++j) {
            h[j] = f2bf(x0[j]);
            h[4 + j] = f2bf(x1[j]);
        }
        const size_t fo = ((size_t)bh * 64 + c) * 2048 + g * 256 + row * 8;
        *reinterpret_cast<us8*>(kf + fo) = h;
    }
    {
        const int row = t >> 3, d0 = (t & 7) * 8;
        const float* src = v + ((size_t)bh * NN + c * 32 + row) * ND + d0;
        f32x4 a = *reinterpret_cast<const f32x4*>(src);
        f32x4 b2 = *reinterpret_cast<const f32x4*>(src + 4);
        *reinterpret_cast<f32x4*>(&T[row][d0]) = a;
        *reinterpret_cast<f32x4*>(&T[row][d0 + 4]) = b2;
    }
    __syncthreads();
    {
        const int g2 = t >> 6, hi = (t >> 5) & 1, l31 = t & 31;
        const int ks2 = g2 & 1, dt = g2 >> 1;
        us8 r;
        #pragma unroll
        for (int j = 0; j < 8; ++j) r[j] = f2bf(T[ks2 * 16 + hi * 8 + j][dt * 32 + l31]);
        const size_t fo = ((size_t)bh * 64 + c) * 2048 + (g2 * 2 + hi) * 256 + l31 * 8;
        *reinterpret_cast<us8*>(vf + fo) = r;
    }
}

// ---------- W -> fragment-major bf16 ----------
__global__ __launch_bounds__(256) void wf_kernel(const float* __restrict__ w,
                                                 unsigned short* __restrict__ wf) {
    const int tid = blockIdx.x * 256 + threadIdx.x;  // 512 blocks
    const int ot = tid >> 11;
    const int s = tid & 2047;
    const int cc = s >> 6;
    const int lane = s & 63;
    const int l15 = lane & 15, lhi = lane >> 4;
    const float* src = w + (size_t)(ot * 16 + l15) * NC + cc * 32 + lhi * 8;
    f32x4 x0 = *reinterpret_cast<const f32x4*>(src);
    f32x4 x1 = *reinterpret_cast<const f32x4*>(src + 4);
    us8 r;
    #pragma unroll
    for (int j = 0; j < 4; ++j) {
        r[j] = f2bf(x0[j]);
        r[4 + j] = f2bf(x1[j]);
    }
    *reinterpret_cast<us8*>(wf + (size_t)tid * 8) = r;
}

// stage chunk CI into buffer BUF
#define STAGE(CI, BUF)                                                   \
    {                                                                    \
        load_lds16(KpT + (size_t)(CI) * 2048, &sK[BUF][wave * 512]);     \
        load_lds16(VpT + (size_t)(CI) * 2048, &sV[BUF][wave * 512]);     \
    }

// one pipelined iteration: compute chunk CI from buffer CUR=(CI&3);
// stage chunk CI+3 into (CI+3)&3; counted vmcnt waits only for chunk CI+1.
#define ATTN_ITER(CI, CUR)                                                             \
    {                                                                                  \
        if ((CI) < 29) STAGE((CI) + 3, ((CUR) + 3) & 3)                                \
        const unsigned short* Kb = &sK[CUR][fo];                                       \
        const unsigned short* Vb = &sV[CUR][fo];                                       \
        f32x16 sa;                                                                     \
        _Pragma("unroll")                                                              \
        for (int r = 0; r < 16; ++r) sa[r] = 0.f;                                      \
        _Pragma("unroll")                                                              \
        for (int ks = 0; ks < 4; ++ks) {                                               \
            bf16x8 kk = *reinterpret_cast<const bf16x8*>(Kb + ks * 512);               \
            sa = MFMA32(kk, qh[ks], sa, 0, 0, 0);                                      \
        }                                                                              \
        _Pragma("unroll")                                                              \
        for (int r = 0; r < 16; r += 4) {                                              \
            float e0 = EX2(sa[r]);                                                     \
            float e1 = EX2(sa[r + 1]);                                                 \
            float e2 = EX2(sa[r + 2]);                                                 \
            float e3 = EX2(sa[r + 3]);                                                 \
            sa[r] = e0; sa[r + 1] = e1; sa[r + 2] = e2; sa[r + 3] = e3;                \
            rs0 += e0; rs1 += e1; rs2 += e2; rs3 += e3;                                \
        }                                                                              \
        _Pragma("unroll")                                                              \
        for (int ks2 = 0; ks2 < 2; ++ks2) {                                            \
            unsigned int sA = pk2(sa[8 * ks2 + 0], sa[8 * ks2 + 1]);                   \
            unsigned int sB = pk2(sa[8 * ks2 + 2], sa[8 * ks2 + 3]);                   \
            unsigned int sC = pk2(sa[8 * ks2 + 4], sa[8 * ks2 + 5]);                   \
            unsigned int sD = pk2(sa[8 * ks2 + 6], sa[8 * ks2 + 7]);                   \
            unsigned int snd0 = hi ? sA : sC;                                          \
            unsigned int snd1 = hi ? sB : sD;                                          \
            unsigned int rcv0 = __shfl_xor(snd0, 32);                                  \
            unsigned int rcv1 = __shfl_xor(snd1, 32);                                  \
            u32x4 uf;                                                                  \
            uf[0] = hi ? rcv0 : sA;                                                    \
            uf[1] = hi ? rcv1 : sB;                                                    \
            uf[2] = hi ? sC : rcv0;                                                    \
            uf[3] = hi ? sD : rcv1;                                                    \
            bf16x8 pfrag = __builtin_bit_cast(bf16x8, uf);                             \
            bf16x8 v0 = *reinterpret_cast<const bf16x8*>(Vb + (0 * 2 + ks2) * 512);    \
            bf16x8 v1 = *reinterpret_cast<const bf16x8*>(Vb + (1 * 2 + ks2) * 512);    \
            acc0 = MFMA32(v0, pfrag, acc0, 0, 0, 0);                                   \
            acc1 = MFMA32(v1, pfrag, acc1, 0, 0, 0);                                   \
        }                                                                              \
        if ((CI) < 31) {                                                               \
            if ((CI) <= 28)      asm volatile("s_waitcnt vmcnt(4)" ::: "memory");      \
            else if ((CI) == 29) asm volatile("s_waitcnt vmcnt(2)" ::: "memory");      \
            else                 asm volatile("s_waitcnt vmcnt(0)" ::: "memory");      \
            __builtin_amdgcn_s_barrier();                                              \
        }                                                                              \
    }

// ---------- fused flash attention: 4-buffer ring, 3-ahead counted-vmcnt pipeline ----------
// grid: 1024 = 32 bh x 16 q-tiles x 2 kv-splits; block 256 (4 waves x 32 q-rows)
__global__ __launch_bounds__(256, 2) void attn_kernel(const float* __restrict__ q,
                                                      const unsigned short* __restrict__ kf,
                                                      const unsigned short* __restrict__ vf,
                                                      unsigned short* __restrict__ po,
                                                      float* __restrict__ pl) {
    __shared__ __align__(16) unsigned short sK[4][2048];
    __shared__ __align__(16) unsigned short sV[4][2048];
    const size_t X_ELEMS = (size_t)NB * NN * NC;
    const size_t ML_ELEMS = (size_t)NB * NN * NH;
    const int bid = blockIdx.x;
    const int swz = (bid & 7) * 128 + (bid >> 3);
    const int bh = swz >> 5;
    const int qt = (swz & 31) >> 1;
    const int split = swz & 1;
    const int b = bh >> 4, h = bh & 15;
    const int t = threadIdx.x;
    const int wave = t >> 6, lane = t & 63;
    const int l31 = lane & 31, hi = lane >> 5;
    const int qrow = qt * 128 + wave * 32 + l31;

    // ---- Q row (x log2e) -> bf16 B-fragments ----
    bf16x8 qh[4];
    {
        const float* qp = q + ((size_t)(b * NN + qrow)) * NC + h * ND;
        #pragma unroll
        for (int ks = 0; ks < 4; ++ks) {
            int d = ks * 16 + hi * 8;
            f32x4 x0 = *reinterpret_cast<const f32x4*>(qp + d);
            f32x4 x1 = *reinterpret_cast<const f32x4*>(qp + d + 4);
            bf16x8 ah;
            #pragma unroll
            for (int j = 0; j < 4; ++j) {
                ah[j] = (short)f2bf_hw(x0[j] * LOG2E);
                ah[4 + j] = (short)f2bf_hw(x1[j] * LOG2E);
            }
            qh[ks] = ah;
        }
    }

    f32x16 acc0, acc1;
    #pragma unroll
    for (int r = 0; r < 16; ++r) { acc0[r] = 0.f; acc1[r] = 0.f; }
    float rs0 = 0.f, rs1 = 0.f, rs2 = 0.f, rs3 = 0.f;

    const unsigned short* KpT = kf + (size_t)(bh * 64 + split * 32) * 2048 + (size_t)t * 8;
    const unsigned short* VpT = vf + (size_t)(bh * 64 + split * 32) * 2048 + (size_t)t * 8;
    const int fo = hi * 256 + l31 * 8;

    // prologue: stage chunks 0,1,2; wait only for chunk 0 (1,2 stay in flight)
    STAGE(0, 0)
    STAGE(1, 1)
    STAGE(2, 2)
    asm volatile("s_waitcnt vmcnt(4)" ::: "memory");
    __builtin_amdgcn_s_barrier();

    for (int base = 0; base < 32; base += 4) {
        ATTN_ITER(base + 0, 0)
        ATTN_ITER(base + 1, 1)
        ATTN_ITER(base + 2, 2)
        ATTN_ITER(base + 3, 3)
    }

    // ---- epilogue: split-local sum, normalize, redistribute, fragment-major store ----
    float rs = (rs0 + rs1) + (rs2 + rs3);
    rs += __shfl_xor(rs, 32);
    const float inv = 1.0f / rs;

    unsigned short* pob = po + (size_t)split * X_ELEMS;
    float* plb = pl + (size_t)split * ML_ELEMS;
    const int el15 = l31 & 15;
    const int nt = b * 128 + qt * 8 + wave * 2 + (l31 >> 4);
    #pragma unroll
    for (int dt = 0; dt < 2; ++dt) {
        const f32x16 a = (dt == 0) ? acc0 : acc1;
        unsigned int P0 = pk2(a[0] * inv, a[1] * inv);
        unsigned int P1 = pk2(a[2] * inv, a[3] * inv);
        unsigned int P2 = pk2(a[4] * inv, a[5] * inv);
        unsigned int P3 = pk2(a[6] * inv, a[7] * inv);
        unsigned int P4 = pk2(a[8] * inv, a[9] * inv);
        unsigned int P5 = pk2(a[10] * inv, a[11] * inv);
        unsigned int P6 = pk2(a[12] * inv, a[13] * inv);
        unsigned int P7 = pk2(a[14] * inv, a[15] * inv);
        unsigned int r0 = __shfl_xor(hi ? P0 : P4, 32);
        unsigned int r1 = __shfl_xor(hi ? P1 : P5, 32);
        unsigned int r2 = __shfl_xor(hi ? P2 : P6, 32);
        unsigned int r3 = __shfl_xor(hi ? P3 : P7, 32);
        u32x4 c0, c1;
        c0[0] = hi ? r0 : P0;
        c0[1] = hi ? r1 : P1;
        c0[2] = hi ? P4 : r0;
        c0[3] = hi ? P5 : r1;
        c1[0] = hi ? r2 : P2;
        c1[1] = hi ? r3 : P3;
        c1[2] = hi ? P6 : r2;
        c1[3] = hi ? P7 : r3;
        unsigned short* base_ = pob + (size_t)(nt * 32 + h * 2 + dt) * 512;
        *reinterpret_cast<u32x4*>(base_ + (hi * 32 + el15) * 8) = c0;
        *reinterpret_cast<u32x4*>(base_ + (hi * 32 + 16 + el15) * 8) = c1;
    }
    if (hi == 0) {
        plb[(size_t)(b * NN + qrow) * NH + h] = rs;
    }
}

// ---------- combine: blend KV-split partials once, fragment-major in/out ----------
__global__ __launch_bounds__(256) void combine_kernel(const unsigned short* __restrict__ po,
                                                      const float* __restrict__ pl,
                                                      unsigned short* __restrict__ xf) {
    const size_t X_ELEMS = (size_t)NB * NN * NC;
    const size_t ML_ELEMS = (size_t)NB * NN * NH;
    const int tid = blockIdx.x * 256 + threadIdx.x;  // 1024 blocks
    const int nt = tid >> 10;
    const int v = tid & 1023;
    const int h = v >> 6;
    const int lane = v & 63;
    const int row = nt * 16 + (lane & 15);
    float w[NSPLIT];
    {
        float lsum = 0.f;
        #pragma unroll
        for (int i = 0; i < NSPLIT; ++i) {
            w[i] = pl[(size_t)i * ML_ELEMS + (size_t)row * NH + h];
            lsum += w[i];
        }
        float inv = 1.0f / lsum;
        #pragma unroll
        for (int i = 0; i < NSPLIT; ++i) w[i] *= inv;
    }
    const size_t s0 = (size_t)(nt * 32 + h * 2) * 512 + lane * 8;
    const size_t s1 = s0 + 512;
    float f0[8], f1[8];
    #pragma unroll
    for (int j = 0; j < 8; ++j) { f0[j] = 0.f; f1[j] = 0.f; }
    #pragma unroll
    for (int i = 0; i < NSPLIT; ++i) {
        us8 e0 = *reinterpret_cast<const us8*>(po + (size_t)i * X_ELEMS + s0);
        us8 e1 = *reinterpret_cast<const us8*>(po + (size_t)i * X_ELEMS + s1);
        #pragma unroll
        for (int j = 0; j < 8; ++j) {
            f0[j] += w[i] * bf2f(e0[j]);
            f1[j] += w[i] * bf2f(e1[j]);
        }
    }
    us8 o0_, o1_;
    #pragma unroll
    for (int j = 0; j < 8; ++j) {
        o0_[j] = f2bf_hw(f0[j]);
        o1_[j] = f2bf_hw(f1[j]);
    }
    *reinterpret_cast<us8*>(xf + s0) = o0_;
    *reinterpret_cast<us8*>(xf + s1) = o1_;
}

// ---------- projection GEMM: pure fragment-major, zero LDS, K-prefetch (R18 version) ----------
__global__ __launch_bounds__(256, 2) void proj_kernel(const unsigned short* __restrict__ xf,
                                                      const unsigned short* __restrict__ wf,
                                                      const float* __restrict__ bias,
                                                      float* __restrict__ out) {
    const int bid = blockIdx.x;
    const int swz = (bid & 7) * 64 + (bid >> 3);
    const int bx = swz >> 4;
    const int by = swz & 15;
    const int wave = threadIdx.x >> 6, lane = threadIdx.x & 63;
    const int l15 = lane & 15, lhi = lane >> 4;
    const int nt0 = bx * 8 + wave * 2;
    const int ot0 = by * 4;

    const unsigned short* xA = xf + (size_t)nt0 * 32 * 512 + lane * 8;
    const unsigned short* xB = xA + 32 * 512;
    const unsigned short* wB = wf + (size_t)ot0 * 32 * 512 + lane * 8;

    f32x4 acc[2][4];
    #pragma unroll
    for (int g = 0; g < 2; ++g)
        #pragma unroll
        for (int c = 0; c < 4; ++c) acc[g][c] = (f32x4){0.f, 0.f, 0.f, 0.f};

    bf16x8 a0 = *reinterpret_cast<const bf16x8*>(xA);
    bf16x8 a1 = *reinterpret_cast<const bf16x8*>(xB);
    bf16x8 bfr[4];
    #pragma unroll
    for (int cb = 0; cb < 4; ++cb)
        bfr[cb] = *reinterpret_cast<const bf16x8*>(wB + (size_t)cb * 32 * 512);

    for (int cc = 0; cc < 32; ++cc) {
        const int ccn = (cc < 31) ? cc + 1 : 31;
        bf16x8 a0n = *reinterpret_cast<const bf16x8*>(xA + (size_t)ccn * 512);
        bf16x8 a1n = *reinterpret_cast<const bf16x8*>(xB + (size_t)ccn * 512);
        bf16x8 bn[4];
        #pragma unroll
        for (int cb = 0; cb < 4; ++cb)
            bn[cb] = *reinterpret_cast<const bf16x8*>(wB + (size_t)(cb * 32 + ccn) * 512);
        #pragma unroll
        for (int cb = 0; cb < 4; ++cb) {
            acc[0][cb] = MFMA16(a0, bfr[cb], acc[0][cb], 0, 0, 0);
            acc[1][cb] = MFMA16(a1, bfr[cb], acc[1][cb], 0, 0, 0);
        }
        a0 = a0n; a1 = a1n;
        #pragma unroll
        for (int cb = 0; cb < 4; ++cb) bfr[cb] = bn[cb];
    }
    #pragma unroll
    for (int g = 0; g < 2; ++g)
        #pragma unroll
        for (int cb = 0; cb < 4; ++cb)
            #pragma unroll
            for (int v = 0; v < 4; ++v) {
                int n = bx * 128 + wave * 32 + g * 16 + lhi * 4 + v;
                int o = by * 64 + cb * 16 + l15;
                out[(size_t)n * NC + o] = acc[g][cb][v] + bias[o];
            }
}

extern "C" void kernel_launch(void* const* d_in, const int* in_sizes, int n_in,
                              void* d_out, int out_size, void* d_ws, size_t ws_size,
                              hipStream_t stream) {
    const float* q    = (const float*)d_in[0];
    const float* k    = (const float*)d_in[1];
    const float* v    = (const float*)d_in[2];
    const float* w    = (const float*)d_in[3];
    const float* bias = (const float*)d_in[4];
    float* out = (float*)d_out;

    const size_t KV_ELEMS = (size_t)NB * NH * NN * ND;  // 4,194,304
    const size_t X_ELEMS  = (size_t)NB * NN * NC;       // 4,194,304
    const size_t W_ELEMS  = (size_t)NC * NC;            // 1,048,576
    const size_t ML_ELEMS = (size_t)NB * NN * NH;       // 65,536

    unsigned short* kfb = (unsigned short*)d_ws;
    unsigned short* vfb = kfb + KV_ELEMS;
    unsigned short* wfb = vfb + KV_ELEMS;
    unsigned short* pob = wfb + W_ELEMS;                 // 2 splits
    unsigned short* xfb = pob + (size_t)NSPLIT * X_ELEMS;
    float* plb = (float*)(xfb + X_ELEMS);                // 2 splits

    dim3 fg(NN / 32, NB * NH);
    kvf_kernel<<<fg, 256, 0, stream>>>(k, v, kfb, vfb);
    wf_kernel<<<512, 256, 0, stream>>>(w, wfb);

    attn_kernel<<<1024, 256, 0, stream>>>(q, kfb, vfb, pob, plb);
    combine_kernel<<<1024, 256, 0, stream>>>(pob, plb, xfb);

    proj_kernel<<<512, 256, 0, stream>>>(xfb, wfb, bias, out);
}

// Round 22
// 88.027 us; speedup vs baseline: 1.1266x; 1.0281x over previous
//
#include <hip/hip_runtime.h>
#include <hip/hip_bf16.h>

#define NB 2
#define NN 2048
#define NC 1024
#define NH 16
#define ND 64
#define LOG2E 1.4426950408889634f
#define NSPLIT 2

typedef __attribute__((ext_vector_type(4))) float f32x4;
typedef __attribute__((ext_vector_type(16))) float f32x16;
typedef __attribute__((ext_vector_type(8))) short bf16x8;
typedef __attribute__((ext_vector_type(4))) unsigned short us4;
typedef __attribute__((ext_vector_type(8))) unsigned short us8;
typedef __attribute__((ext_vector_type(4))) unsigned int u32x4;

#define MFMA32 __builtin_amdgcn_mfma_f32_32x32x16_bf16
#define MFMA16 __builtin_amdgcn_mfma_f32_16x16x32_bf16

// 2^x: compiler-visible intrinsic preferred (R13 lesson)
#if __has_builtin(__builtin_amdgcn_exp2f)
#define EX2(x) __builtin_amdgcn_exp2f(x)
#else
__device__ __forceinline__ float ex2_asm(float x) {
    float r;
    asm volatile("v_exp_f32 %0, %1\n\ts_nop 1" : "=v"(r) : "v"(x));
    return r;
}
#define EX2(x) ex2_asm(x)
#endif

// async global -> LDS, 16B per lane; lds base must be wave-uniform
__device__ __forceinline__ void load_lds16(const unsigned short* g, unsigned short* l) {
    __builtin_amdgcn_global_load_lds(
        (const __attribute__((address_space(1))) unsigned int*)g,
        (__attribute__((address_space(3))) unsigned int*)l, 16, 0, 0);
}

__device__ __forceinline__ unsigned short f2bf(float f) {  // integer RNE
    unsigned int u = __builtin_bit_cast(unsigned int, f);
    u = (u + 0x7FFFu + ((u >> 16) & 1u)) >> 16;
    return (unsigned short)u;
}
__device__ __forceinline__ float bf2f(unsigned short h) {
    return __builtin_bit_cast(float, (unsigned int)h << 16);
}
__device__ __forceinline__ unsigned short f2bf_hw(float f) {
    __hip_bfloat16 b = __float2bfloat16(f);
    unsigned short u;
    __builtin_memcpy(&u, &b, 2);
    return u;
}
// pack two f32 -> dword of 2 bf16, single HW instruction (VOP3 VALU)
__device__ __forceinline__ unsigned int pk2(float lo, float hi) {
    unsigned int r;
    asm("v_cvt_pk_bf16_f32 %0, %1, %2" : "=v"(r) : "v"(lo), "v"(hi));
    return r;
}

// ---------- K, V, W -> fragment-major bf16 (fully fused prep) ----------
// grid (NN/32=64, NB*NH=32), block 256. Threads 0-63 additionally convert
// 64 W-fragment slots (block-linear id * 64 + t covers all 131072 slots).
__global__ __launch_bounds__(256) void kvf_kernel(const float* __restrict__ k,
                                                  const float* __restrict__ v,
                                                  const float* __restrict__ w,
                                                  unsigned short* __restrict__ kf,
                                                  unsigned short* __restrict__ vf,
                                                  unsigned short* __restrict__ wf) {
    __shared__ float T[32][68];
    const int bh = blockIdx.y, c = blockIdx.x, t = threadIdx.x;
    {
        const int row = t >> 3;
        const int g = t & 7;
        const float* src = k + ((size_t)bh * NN + c * 32 + row) * ND + g * 8;
        f32x4 x0 = *reinterpret_cast<const f32x4*>(src);
        f32x4 x1 = *reinterpret_cast<const f32x4*>(src + 4);
        us8 h;
        #pragma unroll
        for (int j = 0; j < 4; ++j) {
            h[j] = f2bf(x0[j]);
            h[4 + j] = f2bf(x1[j]);
        }
        const size_t fo = ((size_t)bh * 64 + c) * 2048 + g * 256 + row * 8;
        *reinterpret_cast<us8*>(kf + fo) = h;
    }
    {
        const int row = t >> 3, d0 = (t & 7) * 8;
        const float* src = v + ((size_t)bh * NN + c * 32 + row) * ND + d0;
        f32x4 a = *reinterpret_cast<const f32x4*>(src);
        f32x4 b2 = *reinterpret_cast<const f32x4*>(src + 4);
        *reinterpret_cast<f32x4*>(&T[row][d0]) = a;
        *reinterpret_cast<f32x4*>(&T[row][d0 + 4]) = b2;
    }
    // W part: one us8 per thread for threads 0-63 (wave-uniform branch)
    if (t < 64) {
        const int wtid = (bh * 64 + c) * 64 + t;
        const int ot = wtid >> 11;
        const int s = wtid & 2047;
        const int cc = s >> 6;
        const int lane = s & 63;
        const int l15 = lane & 15, lhi = lane >> 4;
        const float* src = w + (size_t)(ot * 16 + l15) * NC + cc * 32 + lhi * 8;
        f32x4 x0 = *reinterpret_cast<const f32x4*>(src);
        f32x4 x1 = *reinterpret_cast<const f32x4*>(src + 4);
        us8 r;
        #pragma unroll
        for (int j = 0; j < 4; ++j) {
            r[j] = f2bf(x0[j]);
            r[4 + j] = f2bf(x1[j]);
        }
        *reinterpret_cast<us8*>(wf + (size_t)wtid * 8) = r;
    }
    __syncthreads();
    {
        const int g2 = t >> 6, hi = (t >> 5) & 1, l31 = t & 31;
        const int ks2 = g2 & 1, dt = g2 >> 1;
        us8 r;
        #pragma unroll
        for (int j = 0; j < 8; ++j) r[j] = f2bf(T[ks2 * 16 + hi * 8 + j][dt * 32 + l31]);
        const size_t fo = ((size_t)bh * 64 + c) * 2048 + (g2 * 2 + hi) * 256 + l31 * 8;
        *reinterpret_cast<us8*>(vf + fo) = r;
    }
}

// stage chunk CI into buffer BUF
#define STAGE(CI, BUF)                                                   \
    {                                                                    \
        load_lds16(KpT + (size_t)(CI) * 2048, &sK[BUF][wave * 512]);     \
        load_lds16(VpT + (size_t)(CI) * 2048, &sV[BUF][wave * 512]);     \
    }

// one pipelined iteration (R18 schedule): compute chunk CI from buffer CUR;
// stage chunk CI+2 into NXT2; counted vmcnt keeps newest stage in flight.
#define ATTN_ITER(CI, CUR, NXT2)                                                       \
    {                                                                                  \
        if ((CI) < 30) STAGE((CI) + 2, NXT2);                                          \
        const unsigned short* Kb = &sK[CUR][fo];                                       \
        const unsigned short* Vb = &sV[CUR][fo];                                       \
        f32x16 sa;                                                                     \
        _Pragma("unroll")                                                              \
        for (int r = 0; r < 16; ++r) sa[r] = 0.f;                                      \
        _Pragma("unroll")                                                              \
        for (int ks = 0; ks < 4; ++ks) {                                               \
            bf16x8 kk = *reinterpret_cast<const bf16x8*>(Kb + ks * 512);               \
            sa = MFMA32(kk, qh[ks], sa, 0, 0, 0);                                      \
        }                                                                              \
        _Pragma("unroll")                                                              \
        for (int r = 0; r < 16; r += 4) {                                              \
            float e0 = EX2(sa[r]);                                                     \
            float e1 = EX2(sa[r + 1]);                                                 \
            float e2 = EX2(sa[r + 2]);                                                 \
            float e3 = EX2(sa[r + 3]);                                                 \
            sa[r] = e0; sa[r + 1] = e1; sa[r + 2] = e2; sa[r + 3] = e3;                \
            rs0 += e0; rs1 += e1; rs2 += e2; rs3 += e3;                                \
        }                                                                              \
        _Pragma("unroll")                                                              \
        for (int ks2 = 0; ks2 < 2; ++ks2) {                                            \
            unsigned int sA = pk2(sa[8 * ks2 + 0], sa[8 * ks2 + 1]);                   \
            unsigned int sB = pk2(sa[8 * ks2 + 2], sa[8 * ks2 + 3]);                   \
            unsigned int sC = pk2(sa[8 * ks2 + 4], sa[8 * ks2 + 5]);                   \
            unsigned int sD = pk2(sa[8 * ks2 + 6], sa[8 * ks2 + 7]);                   \
            unsigned int snd0 = hi ? sA : sC;                                          \
            unsigned int snd1 = hi ? sB : sD;                                          \
            unsigned int rcv0 = __shfl_xor(snd0, 32);                                  \
            unsigned int rcv1 = __shfl_xor(snd1, 32);                                  \
            u32x4 uf;                                                                  \
            uf[0] = hi ? rcv0 : sA;                                                    \
            uf[1] = hi ? rcv1 : sB;                                                    \
            uf[2] = hi ? sC : rcv0;                                                    \
            uf[3] = hi ? sD : rcv1;                                                    \
            bf16x8 pfrag = __builtin_bit_cast(bf16x8, uf);                             \
            bf16x8 v0 = *reinterpret_cast<const bf16x8*>(Vb + (0 * 2 + ks2) * 512);    \
            bf16x8 v1 = *reinterpret_cast<const bf16x8*>(Vb + (1 * 2 + ks2) * 512);    \
            acc0 = MFMA32(v0, pfrag, acc0, 0, 0, 0);                                   \
            acc1 = MFMA32(v1, pfrag, acc1, 0, 0, 0);                                   \
        }                                                                              \
        if ((CI) < 31) {                                                               \
            if ((CI) == 30) asm volatile("s_waitcnt vmcnt(0)" ::: "memory");           \
            else            asm volatile("s_waitcnt vmcnt(2)" ::: "memory");           \
            __builtin_amdgcn_s_barrier();                                              \
        }                                                                              \
    }

// ---------- fused flash attention: counted-vmcnt 3-buffer LDS pipeline (R18 best) ----------
// grid: 1024 = 32 bh x 16 q-tiles x 2 kv-splits; block 256 (4 waves x 32 q-rows)
__global__ __launch_bounds__(256, 2) void attn_kernel(const float* __restrict__ q,
                                                      const unsigned short* __restrict__ kf,
                                                      const unsigned short* __restrict__ vf,
                                                      unsigned short* __restrict__ po,
                                                      float* __restrict__ pl) {
    __shared__ __align__(16) unsigned short sK[3][2048];
    __shared__ __align__(16) unsigned short sV[3][2048];
    const size_t X_ELEMS = (size_t)NB * NN * NC;
    const size_t ML_ELEMS = (size_t)NB * NN * NH;
    const int bid = blockIdx.x;
    const int swz = (bid & 7) * 128 + (bid >> 3);
    const int bh = swz >> 5;
    const int qt = (swz & 31) >> 1;
    const int split = swz & 1;
    const int b = bh >> 4, h = bh & 15;
    const int t = threadIdx.x;
    const int wave = t >> 6, lane = t & 63;
    const int l31 = lane & 31, hi = lane >> 5;
    const int qrow = qt * 128 + wave * 32 + l31;

    // ---- Q row (x log2e) -> bf16 B-fragments ----
    bf16x8 qh[4];
    {
        const float* qp = q + ((size_t)(b * NN + qrow)) * NC + h * ND;
        #pragma unroll
        for (int ks = 0; ks < 4; ++ks) {
            int d = ks * 16 + hi * 8;
            f32x4 x0 = *reinterpret_cast<const f32x4*>(qp + d);
            f32x4 x1 = *reinterpret_cast<const f32x4*>(qp + d + 4);
            bf16x8 ah;
            #pragma unroll
            for (int j = 0; j < 4; ++j) {
                ah[j] = (short)f2bf_hw(x0[j] * LOG2E);
                ah[4 + j] = (short)f2bf_hw(x1[j] * LOG2E);
            }
            qh[ks] = ah;
        }
    }

    f32x16 acc0, acc1;
    #pragma unroll
    for (int r = 0; r < 16; ++r) { acc0[r] = 0.f; acc1[r] = 0.f; }
    float rs0 = 0.f, rs1 = 0.f, rs2 = 0.f, rs3 = 0.f;

    const unsigned short* KpT = kf + (size_t)(bh * 64 + split * 32) * 2048 + (size_t)t * 8;
    const unsigned short* VpT = vf + (size_t)(bh * 64 + split * 32) * 2048 + (size_t)t * 8;
    const int fo = hi * 256 + l31 * 8;

    // prologue: stage chunks 0,1; wait only for chunk 0
    STAGE(0, 0)
    STAGE(1, 1)
    asm volatile("s_waitcnt vmcnt(2)" ::: "memory");
    __builtin_amdgcn_s_barrier();

    for (int base = 0; base < 30; base += 3) {
        ATTN_ITER(base, 0, 2)
        ATTN_ITER(base + 1, 1, 0)
        ATTN_ITER(base + 2, 2, 1)
    }
    ATTN_ITER(30, 0, 2)
    ATTN_ITER(31, 1, 0)

    // ---- epilogue: split-local sum, normalize, redistribute, fragment-major store ----
    float rs = (rs0 + rs1) + (rs2 + rs3);
    rs += __shfl_xor(rs, 32);
    const float inv = 1.0f / rs;

    unsigned short* pob = po + (size_t)split * X_ELEMS;
    float* plb = pl + (size_t)split * ML_ELEMS;
    const int el15 = l31 & 15;
    const int nt = b * 128 + qt * 8 + wave * 2 + (l31 >> 4);
    #pragma unroll
    for (int dt = 0; dt < 2; ++dt) {
        const f32x16 a = (dt == 0) ? acc0 : acc1;
        unsigned int P0 = pk2(a[0] * inv, a[1] * inv);
        unsigned int P1 = pk2(a[2] * inv, a[3] * inv);
        unsigned int P2 = pk2(a[4] * inv, a[5] * inv);
        unsigned int P3 = pk2(a[6] * inv, a[7] * inv);
        unsigned int P4 = pk2(a[8] * inv, a[9] * inv);
        unsigned int P5 = pk2(a[10] * inv, a[11] * inv);
        unsigned int P6 = pk2(a[12] * inv, a[13] * inv);
        unsigned int P7 = pk2(a[14] * inv, a[15] * inv);
        unsigned int r0 = __shfl_xor(hi ? P0 : P4, 32);
        unsigned int r1 = __shfl_xor(hi ? P1 : P5, 32);
        unsigned int r2 = __shfl_xor(hi ? P2 : P6, 32);
        unsigned int r3 = __shfl_xor(hi ? P3 : P7, 32);
        u32x4 c0, c1;
        c0[0] = hi ? r0 : P0;
        c0[1] = hi ? r1 : P1;
        c0[2] = hi ? P4 : r0;
        c0[3] = hi ? P5 : r1;
        c1[0] = hi ? r2 : P2;
        c1[1] = hi ? r3 : P3;
        c1[2] = hi ? P6 : r2;
        c1[3] = hi ? P7 : r3;
        unsigned short* base_ = pob + (size_t)(nt * 32 + h * 2 + dt) * 512;
        *reinterpret_cast<u32x4*>(base_ + (hi * 32 + el15) * 8) = c0;
        *reinterpret_cast<u32x4*>(base_ + (hi * 32 + 16 + el15) * 8) = c1;
    }
    if (hi == 0) {
        plb[(size_t)(b * NN + qrow) * NH + h] = rs;
    }
}

// ---------- combine: blend KV-split partials once, fragment-major in/out ----------
__global__ __launch_bounds__(256) void combine_kernel(const unsigned short* __restrict__ po,
                                                      const float* __restrict__ pl,
                                                      unsigned short* __restrict__ xf) {
    const size_t X_ELEMS = (size_t)NB * NN * NC;
    const size_t ML_ELEMS = (size_t)NB * NN * NH;
    const int tid = blockIdx.x * 256 + threadIdx.x;  // 1024 blocks
    const int nt = tid >> 10;
    const int v = tid & 1023;
    const int h = v >> 6;
    const int lane = v & 63;
    const int row = nt * 16 + (lane & 15);
    float w[NSPLIT];
    {
        float lsum = 0.f;
        #pragma unroll
        for (int i = 0; i < NSPLIT; ++i) {
            w[i] = pl[(size_t)i * ML_ELEMS + (size_t)row * NH + h];
            lsum += w[i];
        }
        float inv = 1.0f / lsum;
        #pragma unroll
        for (int i = 0; i < NSPLIT; ++i) w[i] *= inv;
    }
    const size_t s0 = (size_t)(nt * 32 + h * 2) * 512 + lane * 8;
    const size_t s1 = s0 + 512;
    float f0[8], f1[8];
    #pragma unroll
    for (int j = 0; j < 8; ++j) { f0[j] = 0.f; f1[j] = 0.f; }
    #pragma unroll
    for (int i = 0; i < NSPLIT; ++i) {
        us8 e0 = *reinterpret_cast<const us8*>(po + (size_t)i * X_ELEMS + s0);
        us8 e1 = *reinterpret_cast<const us8*>(po + (size_t)i * X_ELEMS + s1);
        #pragma unroll
        for (int j = 0; j < 8; ++j) {
            f0[j] += w[i] * bf2f(e0[j]);
            f1[j] += w[i] * bf2f(e1[j]);
        }
    }
    us8 o0_, o1_;
    #pragma unroll
    for (int j = 0; j < 8; ++j) {
        o0_[j] = f2bf_hw(f0[j]);
        o1_[j] = f2bf_hw(f1[j]);
    }
    *reinterpret_cast<us8*>(xf + s0) = o0_;
    *reinterpret_cast<us8*>(xf + s1) = o1_;
}

// ---------- projection GEMM: pure fragment-major, zero LDS, K-prefetch (R18) ----------
__global__ __launch_bounds__(256, 2) void proj_kernel(const unsigned short* __restrict__ xf,
                                                      const unsigned short* __restrict__ wf,
                                                      const float* __restrict__ bias,
                                                      float* __restrict__ out) {
    const int bid = blockIdx.x;
    const int swz = (bid & 7) * 64 + (bid >> 3);
    const int bx = swz >> 4;
    const int by = swz & 15;
    const int wave = threadIdx.x >> 6, lane = threadIdx.x & 63;
    const int l15 = lane & 15, lhi = lane >> 4;
    const int nt0 = bx * 8 + wave * 2;
    const int ot0 = by * 4;

    const unsigned short* xA = xf + (size_t)nt0 * 32 * 512 + lane * 8;
    const unsigned short* xB = xA + 32 * 512;
    const unsigned short* wB = wf + (size_t)ot0 * 32 * 512 + lane * 8;

    f32x4 acc[2][4];
    #pragma unroll
    for (int g = 0; g < 2; ++g)
        #pragma unroll
        for (int c = 0; c < 4; ++c) acc[g][c] = (f32x4){0.f, 0.f, 0.f, 0.f};

    bf16x8 a0 = *reinterpret_cast<const bf16x8*>(xA);
    bf16x8 a1 = *reinterpret_cast<const bf16x8*>(xB);
    bf16x8 bfr[4];
    #pragma unroll
    for (int cb = 0; cb < 4; ++cb)
        bfr[cb] = *reinterpret_cast<const bf16x8*>(wB + (size_t)cb * 32 * 512);

    for (int cc = 0; cc < 32; ++cc) {
        const int ccn = (cc < 31) ? cc + 1 : 31;
        bf16x8 a0n = *reinterpret_cast<const bf16x8*>(xA + (size_t)ccn * 512);
        bf16x8 a1n = *reinterpret_cast<const bf16x8*>(xB + (size_t)ccn * 512);
        bf16x8 bn[4];
        #pragma unroll
        for (int cb = 0; cb < 4; ++cb)
            bn[cb] = *reinterpret_cast<const bf16x8*>(wB + (size_t)(cb * 32 + ccn) * 512);
        #pragma unroll
        for (int cb = 0; cb < 4; ++cb) {
            acc[0][cb] = MFMA16(a0, bfr[cb], acc[0][cb], 0, 0, 0);
            acc[1][cb] = MFMA16(a1, bfr[cb], acc[1][cb], 0, 0, 0);
        }
        a0 = a0n; a1 = a1n;
        #pragma unroll
        for (int cb = 0; cb < 4; ++cb) bfr[cb] = bn[cb];
    }
    #pragma unroll
    for (int g = 0; g < 2; ++g)
        #pragma unroll
        for (int cb = 0; cb < 4; ++cb)
            #pragma unroll
            for (int v = 0; v < 4; ++v) {
                int n = bx * 128 + wave * 32 + g * 16 + lhi * 4 + v;
                int o = by * 64 + cb * 16 + l15;
                out[(size_t)n * NC + o] = acc[g][cb][v] + bias[o];
            }
}

extern "C" void kernel_launch(void* const* d_in, const int* in_sizes, int n_in,
                              void* d_out, int out_size, void* d_ws, size_t ws_size,
                              hipStream_t stream) {
    const float* q    = (const float*)d_in[0];
    const float* k    = (const float*)d_in[1];
    const float* v    = (const float*)d_in[2];
    const float* w    = (const float*)d_in[3];
    const float* bias = (const float*)d_in[4];
    float* out = (float*)d_out;

    const size_t KV_ELEMS = (size_t)NB * NH * NN * ND;  // 4,194,304
    const size_t X_ELEMS  = (size_t)NB * NN * NC;       // 4,194,304
    const size_t W_ELEMS  = (size_t)NC * NC;            // 1,048,576
    const size_t ML_ELEMS = (size_t)NB * NN * NH;       // 65,536

    unsigned short* kfb = (unsigned short*)d_ws;
    unsigned short* vfb = kfb + KV_ELEMS;
    unsigned short* wfb = vfb + KV_ELEMS;
    unsigned short* pob = wfb + W_ELEMS;                 // 2 splits
    unsigned short* xfb = pob + (size_t)NSPLIT * X_ELEMS;
    float* plb = (float*)(xfb + X_ELEMS);                // 2 splits

    dim3 fg(NN / 32, NB * NH);
    kvf_kernel<<<fg, 256, 0, stream>>>(k, v, w, kfb, vfb, wfb);

    attn_kernel<<<1024, 256, 0, stream>>>(q, kfb, vfb, pob, plb);
    combine_kernel<<<1024, 256, 0, stream>>>(pob, plb, xfb);

    proj_kernel<<<512, 256, 0, stream>>>(xfb, wfb, bias, out);
}